// Round 11
// baseline (1153.005 us; speedup 1.0000x reference)
//
#include <hip/hip_runtime.h>
#include <hip/hip_bf16.h>

#define GN 50000
#define GE 800000
#define FIN 128
#define GH 256
#define GB 128
#define NCLS 10
#define GSCALE 3
#define GNNZ 1200000
#define NSEG (GSCALE * GB)  // 384
#define PAD 16              // ints per counter slot (64B line) to kill false sharing

// ---------------- degree / dinv ----------------
__global__ __launch_bounds__(256) void deg_count_kernel(const int* __restrict__ dst,
                                                        int* __restrict__ deg) {
  int i = blockIdx.x * 256 + threadIdx.x;
  if (i < GE) atomicAdd(&deg[dst[i]], 1);
}

__global__ __launch_bounds__(256) void dinv_kernel(const int* __restrict__ deg,
                                                   float* __restrict__ dinv) {
  int i = blockIdx.x * 256 + threadIdx.x;
  if (i < GN) dinv[i] = 1.0f / sqrtf((float)(deg[i] + 1));  // self-loop => deg+1 >= 1
}

// ---------------- hierarchical exclusive scan (n up to GN) ----------------
__global__ __launch_bounds__(256) void scan1_kernel(const int* __restrict__ in,
                                                    int* __restrict__ out,
                                                    int* __restrict__ btot, int n) {
  __shared__ int sh[256];
  int b = blockIdx.x, tid = threadIdx.x;
  int i = b * 256 + tid;
  int v = (i < n) ? in[i] : 0;
  sh[tid] = v;
  __syncthreads();
  for (int ofs = 1; ofs < 256; ofs <<= 1) {
    int t = (tid >= ofs) ? sh[tid - ofs] : 0;
    __syncthreads();
    sh[tid] += t;
    __syncthreads();
  }
  if (i < n) out[i] = sh[tid] - v;  // block-local exclusive
  if (tid == 255) btot[b] = sh[255];
}

__global__ __launch_bounds__(256) void scan2_kernel(int* __restrict__ btot, int nb) {
  __shared__ int sh[256];
  int tid = threadIdx.x;
  int v = (tid < nb) ? btot[tid] : 0;
  sh[tid] = v;
  __syncthreads();
  for (int ofs = 1; ofs < 256; ofs <<= 1) {
    int t = (tid >= ofs) ? sh[tid - ofs] : 0;
    __syncthreads();
    sh[tid] += t;
    __syncthreads();
  }
  if (tid < nb) btot[tid] = sh[tid] - v;  // exclusive block bases
}

__global__ __launch_bounds__(256) void scan3_kernel(int* __restrict__ out,
                                                    const int* __restrict__ btot,
                                                    int n, int total) {
  int b = blockIdx.x, tid = threadIdx.x;
  int i = b * 256 + tid;
  if (i < n) out[i] += btot[b];
  if (i == 0) out[n] = total;
}

// ------------- small strided exclusive scan (n <= few hundred) -------------
__global__ __launch_bounds__(256) void exscan_strided_kernel(const int* __restrict__ in,
                                                             int* __restrict__ out,
                                                             int n, int stride) {
  __shared__ int sh[256];
  __shared__ int carry;
  int tid = threadIdx.x;
  if (tid == 0) carry = 0;
  __syncthreads();
  for (int base = 0; base < n; base += 256) {
    int i = base + tid;
    int v = (i < n) ? in[(size_t)i * stride] : 0;
    sh[tid] = v;
    __syncthreads();
    for (int ofs = 1; ofs < 256; ofs <<= 1) {
      int t = (tid >= ofs) ? sh[tid - ofs] : 0;
      __syncthreads();
      sh[tid] += t;
      __syncthreads();
    }
    if (i < n) out[i] = carry + sh[tid] - v;
    int total = sh[255];
    __syncthreads();
    if (tid == 0) carry += total;
    __syncthreads();
  }
  if (tid == 0) out[n] = carry;
}

// ---------------- CSR fill (bucket edges by dst) ----------------
__global__ __launch_bounds__(256) void csr_fill_kernel(const int* __restrict__ src,
                                                       const int* __restrict__ dst,
                                                       int* __restrict__ cur,
                                                       int* __restrict__ csr_src) {
  int i = blockIdx.x * 256 + threadIdx.x;
  if (i < GE) {
    int j = atomicAdd(&cur[dst[i]], 1);
    csr_src[j] = src[i];
  }
}

// ---------------- seg bucketing for wavelet+pool (PADDED counters) ----------------
__device__ __forceinline__ int seg_of(int row, const int* __restrict__ batch) {
  int sc = row / GN;
  int node = row - sc * GN;
  return sc * GB + batch[node];
}

__global__ __launch_bounds__(256) void seg_cnt_kernel(const int* __restrict__ rows,
                                                      const int* __restrict__ batch,
                                                      int* __restrict__ scnt_p) {
  int i = blockIdx.x * 256 + threadIdx.x;
  if (i < GNNZ) atomicAdd(&scnt_p[(size_t)seg_of(rows[i], batch) * PAD], 1);
}

__global__ __launch_bounds__(256) void scur_init_kernel(const int* __restrict__ soff,
                                                        int* __restrict__ scur_p) {
  int s = blockIdx.x * 256 + threadIdx.x;
  if (s < NSEG) scur_p[(size_t)s * PAD] = soff[s];
}

__global__ __launch_bounds__(256) void seg_fill_kernel(const int* __restrict__ rows,
                                                       const int* __restrict__ cols,
                                                       const float* __restrict__ d,
                                                       const int* __restrict__ batch,
                                                       int* __restrict__ scur_p,
                                                       int* __restrict__ scol,
                                                       float* __restrict__ sd) {
  int i = blockIdx.x * 256 + threadIdx.x;
  if (i < GNNZ) {
    int j = atomicAdd(&scur_p[(size_t)seg_of(rows[i], batch) * PAD], 1);
    scol[j] = cols[i];
    sd[j] = d[i];
  }
}

// -------- fp32 GEMM v2: 128x128 tile, 8x8 acc/thread (2x2 of 4x4) --------
// FLOP:LDS-float = 8 (vs 4 in the 64x64/4x4 version). As is k-major with
// stride 132 (pad 4) -> staging stores alias max 2 lanes/bank (free, m136).
template <int K>
__global__ __launch_bounds__(256) void gemm2_kernel(const float* __restrict__ A,
                                                    const float* __restrict__ W,
                                                    float* __restrict__ C, int M) {
  __shared__ float As[16][132];  // As[k][r]
  __shared__ float Bs[16][128];  // Bs[k][c]
  int tid = threadIdx.x;
  int col0 = blockIdx.x * 128;
  int row0 = blockIdx.y * 128;
  int tx = tid & 15, ty = tid >> 4;
  float acc[2][2][4][4] = {};
  for (int kk = 0; kk < K; kk += 16) {
    __syncthreads();  // previous-iter reads done before overwrite
#pragma unroll
    for (int l = 0; l < 2; ++l) {
      int idx = tid + l * 256;
      int r = idx >> 2, q = idx & 3;
      int arow = row0 + r; if (arow >= M) arow = M - 1;
      float4 av = *(const float4*)&A[(size_t)arow * K + kk + q * 4];
      As[q * 4 + 0][r] = av.x;
      As[q * 4 + 1][r] = av.y;
      As[q * 4 + 2][r] = av.z;
      As[q * 4 + 3][r] = av.w;
      int bk = idx >> 5, c4 = idx & 31;
      float4 bv = *(const float4*)&W[(size_t)(kk + bk) * GH + col0 + c4 * 4];
      *(float4*)&Bs[bk][c4 * 4] = bv;
    }
    __syncthreads();
#pragma unroll
    for (int k = 0; k < 16; ++k) {
      float4 a0 = *(const float4*)&As[k][ty * 4];
      float4 a1 = *(const float4*)&As[k][64 + ty * 4];
      float4 b0 = *(const float4*)&Bs[k][tx * 4];
      float4 b1 = *(const float4*)&Bs[k][64 + tx * 4];
      float ar[2][4] = {{a0.x, a0.y, a0.z, a0.w}, {a1.x, a1.y, a1.z, a1.w}};
      float br[2][4] = {{b0.x, b0.y, b0.z, b0.w}, {b1.x, b1.y, b1.z, b1.w}};
#pragma unroll
      for (int p = 0; p < 2; ++p)
#pragma unroll
        for (int qq = 0; qq < 2; ++qq)
#pragma unroll
          for (int i = 0; i < 4; ++i)
#pragma unroll
            for (int j = 0; j < 4; ++j)
              acc[p][qq][i][j] += ar[p][i] * br[qq][j];
    }
  }
#pragma unroll
  for (int p = 0; p < 2; ++p)
#pragma unroll
    for (int i = 0; i < 4; ++i) {
      int r = row0 + p * 64 + ty * 4 + i;
      if (r < M) {
#pragma unroll
        for (int qq = 0; qq < 2; ++qq) {
          float4 v = make_float4(acc[p][qq][i][0], acc[p][qq][i][1],
                                 acc[p][qq][i][2], acc[p][qq][i][3]);
          *(float4*)&C[(size_t)r * GH + col0 + qq * 64 + tx * 4] = v;
        }
      }
    }
}

// ------------- GCN aggregation: gather + self-loop + bias + relu -------------
__global__ __launch_bounds__(256) void agg_kernel(const float* __restrict__ m,
                                                  const float* __restrict__ dinv,
                                                  const int* __restrict__ off,
                                                  const int* __restrict__ srcs,
                                                  const float* __restrict__ bias,
                                                  float* __restrict__ out) {
  int node = blockIdx.x * 4 + (threadIdx.x >> 6);
  if (node >= GN) return;
  int lane = threadIdx.x & 63;
  float4 acc = *(const float4*)&bias[lane * 4];
  float di = dinv[node];
  float w0 = di * di;  // self-loop norm
  float4 mv = *(const float4*)&m[(size_t)node * GH + lane * 4];
  acc.x += w0 * mv.x; acc.y += w0 * mv.y; acc.z += w0 * mv.z; acc.w += w0 * mv.w;
  int e0 = off[node], e1 = off[node + 1];
  int e = e0;
  for (; e + 2 <= e1; e += 2) {  // unroll-by-2: two row loads in flight
    int s0 = srcs[e], s1 = srcs[e + 1];
    float w0a = di * dinv[s0];
    float w1a = di * dinv[s1];
    float4 v0 = *(const float4*)&m[(size_t)s0 * GH + lane * 4];
    float4 v1 = *(const float4*)&m[(size_t)s1 * GH + lane * 4];
    acc.x += w0a * v0.x + w1a * v1.x;
    acc.y += w0a * v0.y + w1a * v1.y;
    acc.z += w0a * v0.z + w1a * v1.z;
    acc.w += w0a * v0.w + w1a * v1.w;
  }
  if (e < e1) {
    int s = srcs[e];
    float w = di * dinv[s];
    float4 v = *(const float4*)&m[(size_t)s * GH + lane * 4];
    acc.x += w * v.x; acc.y += w * v.y; acc.z += w * v.z; acc.w += w * v.w;
  }
  acc.x = fmaxf(acc.x, 0.f); acc.y = fmaxf(acc.y, 0.f);
  acc.z = fmaxf(acc.z, 0.f); acc.w = fmaxf(acc.w, 0.f);
  *(float4*)&out[(size_t)node * GH + lane * 4] = acc;
}

// ------- fused wavelet transform + per-(scale,graph) pooling gather -------
// MEASURED 162-164 us (r2, r10). Staged 256-nnz chunks -> fixed-trip inner loop
// gives the compiler 256 independent h-row loads to pipeline. Read-once
// LDS-scatter variants (r7/r9) collapsed to ~1.5 ms: dependent pk->h->ds_add
// chains get NO compiler MLP. Do not retry without explicit register prefetch.
__global__ __launch_bounds__(256) void pooled_kernel(const float* __restrict__ h,
                                                     const int* __restrict__ soff,
                                                     const int* __restrict__ scol,
                                                     const float* __restrict__ sd,
                                                     float* __restrict__ pooled) {
  __shared__ int lcol[256];
  __shared__ float ld[256];
  int seg = blockIdx.x;
  int j0 = soff[seg], j1 = soff[seg + 1];
  int cnt = j1 - j0;
  int nparts = gridDim.y;
  int per = (cnt + nparts - 1) / nparts;
  int s = j0 + blockIdx.y * per;
  int e = s + per;
  if (e > j1) e = j1;
  int tid = threadIdx.x;
  float acc = 0.f;
  for (int base = s; base < e; base += 256) {
    int nload = e - base;
    if (nload > 256) nload = 256;
    __syncthreads();
    if (tid < nload) {
      lcol[tid] = scol[base + tid];
      ld[tid] = sd[base + tid];
    }
    __syncthreads();
    for (int t = 0; t < nload; ++t) {
      acc += ld[t] * h[(size_t)lcol[t] * GH + tid];
    }
  }
  atomicAdd(&pooled[(size_t)seg * GH + tid], acc);
}

// ---------------- FC head ----------------
__global__ __launch_bounds__(256) void fc1_kernel(const float* __restrict__ pooled,
                                                  const float* __restrict__ w,
                                                  const float* __restrict__ b,
                                                  float* __restrict__ z1) {
  __shared__ float vin[GSCALE * GH];  // 768
  int g = blockIdx.x, tid = threadIdx.x;
#pragma unroll
  for (int it = 0; it < GSCALE; ++it)
    vin[it * GH + tid] = pooled[(size_t)(it * GB + g) * GH + tid];
  __syncthreads();
  float acc = b[tid];
  for (int j = 0; j < GSCALE * GH; ++j) acc += vin[j] * w[(size_t)j * GH + tid];
  z1[(size_t)g * GH + tid] = fmaxf(acc, 0.f);
}

__global__ __launch_bounds__(128) void fc2_kernel(const float* __restrict__ z1,
                                                  const float* __restrict__ w,
                                                  const float* __restrict__ b,
                                                  float* __restrict__ z2) {
  __shared__ float vin[GH];
  int g = blockIdx.x, tid = threadIdx.x;  // 128 threads
  vin[tid] = z1[(size_t)g * GH + tid];
  vin[128 + tid] = z1[(size_t)g * GH + 128 + tid];
  __syncthreads();
  float acc = b[tid];
  for (int j = 0; j < GH; ++j) acc += vin[j] * w[(size_t)j * 128 + tid];
  z2[(size_t)g * 128 + tid] = fmaxf(acc, 0.f);
}

__global__ __launch_bounds__(128) void fc3_kernel(const float* __restrict__ z2,
                                                  const float* __restrict__ w,
                                                  const float* __restrict__ b,
                                                  float* __restrict__ out) {
  int g = threadIdx.x;  // one thread per graph, 1 block of 128
  float logit[NCLS];
#pragma unroll
  for (int o = 0; o < NCLS; ++o) logit[o] = b[o];
  for (int k = 0; k < 128; ++k) {
    float zv = z2[(size_t)g * 128 + k];
#pragma unroll
    for (int o = 0; o < NCLS; ++o) logit[o] += zv * w[k * NCLS + o];
  }
  float mx = logit[0];
#pragma unroll
  for (int o = 1; o < NCLS; ++o) mx = fmaxf(mx, logit[o]);
  float lse = 0.f;
#pragma unroll
  for (int o = 0; o < NCLS; ++o) lse += expf(logit[o] - mx);
  lse = logf(lse);
#pragma unroll
  for (int o = 0; o < NCLS; ++o) out[(size_t)g * NCLS + o] = logit[o] - mx - lse;
}

// ---------------- launch ----------------
static inline size_t alignup(size_t x) { return (x + 1023) & ~(size_t)1023; }

extern "C" void kernel_launch(void* const* d_in, const int* in_sizes, int n_in,
                              void* d_out, int out_size, void* d_ws, size_t ws_size,
                              hipStream_t stream) {
  const float* x      = (const float*)d_in[0];
  const float* W1     = (const float*)d_in[1];
  const float* b1     = (const float*)d_in[2];
  const float* W2     = (const float*)d_in[3];
  const float* b2     = (const float*)d_in[4];
  const float* W3     = (const float*)d_in[5];
  const float* b3     = (const float*)d_in[6];
  const float* fc1w   = (const float*)d_in[7];
  const float* fc1b   = (const float*)d_in[8];
  const float* fc2w   = (const float*)d_in[9];
  const float* fc2b   = (const float*)d_in[10];
  const float* fc3w   = (const float*)d_in[11];
  const float* fc3b   = (const float*)d_in[12];
  const float* dval   = (const float*)d_in[13];
  const int* eidx     = (const int*)d_in[14];
  const int* batch    = (const int*)d_in[15];
  const int* didx     = (const int*)d_in[16];
  float* out          = (float*)d_out;

  const int* esrc = eidx;             // edge_index[0]
  const int* edst = eidx + GE;        // edge_index[1]
  const int* nzrow = didx;            // d_index[0]
  const int* nzcol = didx + GNNZ;     // d_index[1]

  // workspace carve-up
  char* ws = (char*)d_ws;
  size_t o = 0;
  auto take = [&](size_t bytes) { char* p = ws + o; o += alignup(bytes); return p; };
  int*   deg     = (int*)take(GN * 4);
  int*   off     = (int*)take((GN + 1) * 4);
  int*   cur     = (int*)take(GN * 4);
  int*   btot    = (int*)take(256 * 4);
  float* dinv    = (float*)take(GN * 4);
  int*   csr_src = (int*)take(GE * 4);
  int*   scnt_p  = (int*)take(NSEG * PAD * 4);
  int*   soff    = (int*)take((NSEG + 1) * 4);
  int*   scur_p  = (int*)take(NSEG * PAD * 4);
  int*   scol    = (int*)take((size_t)GNNZ * 4);
  float* sd      = (float*)take((size_t)GNNZ * 4);
  float* mbuf    = (float*)take((size_t)GN * GH * 4);
  float* hA      = (float*)take((size_t)GN * GH * 4);
  float* hB      = (float*)take((size_t)GN * GH * 4);
  float* pooled  = (float*)take((size_t)NSEG * GH * 4);
  float* z1      = (float*)take((size_t)GB * GH * 4);
  float* z2      = (float*)take((size_t)GB * 128 * 4);
  (void)ws_size; (void)n_in; (void)in_sizes; (void)out_size;

  const int NB = (GN + 255) / 256;  // 196

  // ---- graph prep (once per call) ----
  hipMemsetAsync(deg, 0, GN * 4, stream);
  hipMemsetAsync(scnt_p, 0, NSEG * PAD * 4, stream);
  hipMemsetAsync(pooled, 0, (size_t)NSEG * GH * 4, stream);

  deg_count_kernel<<<GE / 256, 256, 0, stream>>>(edst, deg);
  dinv_kernel<<<NB, 256, 0, stream>>>(deg, dinv);
  scan1_kernel<<<NB, 256, 0, stream>>>(deg, off, btot, GN);
  scan2_kernel<<<1, 256, 0, stream>>>(btot, NB);
  scan3_kernel<<<NB, 256, 0, stream>>>(off, btot, GN, GE);
  hipMemcpyAsync(cur, off, GN * 4, hipMemcpyDeviceToDevice, stream);
  csr_fill_kernel<<<GE / 256, 256, 0, stream>>>(esrc, edst, cur, csr_src);

  seg_cnt_kernel<<<(GNNZ + 255) / 256, 256, 0, stream>>>(nzrow, batch, scnt_p);
  exscan_strided_kernel<<<1, 256, 0, stream>>>(scnt_p, soff, NSEG, PAD);
  scur_init_kernel<<<(NSEG + 255) / 256, 256, 0, stream>>>(soff, scur_p);
  seg_fill_kernel<<<(GNNZ + 255) / 256, 256, 0, stream>>>(nzrow, nzcol, dval, batch,
                                                          scur_p, scol, sd);

  // ---- 3 GCN layers (gemm2: 128x128 tile) ----
  dim3 ggrid2(GH / 128, (GN + 127) / 128);  // (2, 391)
  gemm2_kernel<FIN><<<ggrid2, 256, 0, stream>>>(x, W1, mbuf, GN);
  agg_kernel<<<(GN + 3) / 4, 256, 0, stream>>>(mbuf, dinv, off, csr_src, b1, hA);
  gemm2_kernel<GH><<<ggrid2, 256, 0, stream>>>(hA, W2, mbuf, GN);
  agg_kernel<<<(GN + 3) / 4, 256, 0, stream>>>(mbuf, dinv, off, csr_src, b2, hB);
  gemm2_kernel<GH><<<ggrid2, 256, 0, stream>>>(hB, W3, mbuf, GN);
  agg_kernel<<<(GN + 3) / 4, 256, 0, stream>>>(mbuf, dinv, off, csr_src, b3, hA);

  // ---- fused wavelet + pooling (hA holds final node features) ----
  pooled_kernel<<<dim3(NSEG, 8), 256, 0, stream>>>(hA, soff, scol, sd, pooled);

  // ---- FC head ----
  fc1_kernel<<<GB, 256, 0, stream>>>(pooled, fc1w, fc1b, z1);
  fc2_kernel<<<GB, 128, 0, stream>>>(z1, fc2w, fc2b, z2);
  fc3_kernel<<<1, 128, 0, stream>>>(z2, fc3w, fc3b, out);
}

// Round 13
// 1046.955 us; speedup vs baseline: 1.1013x; 1.1013x over previous
//
#include <hip/hip_runtime.h>
#include <hip/hip_bf16.h>

#define GN 50000
#define GE 800000
#define FIN 128
#define GH 256
#define GB 128
#define NCLS 10
#define GSCALE 3
#define GNNZ 1200000
#define NSEG (GSCALE * GB)  // 384
#define PAD 16              // ints per counter slot (64B line) to kill false sharing

typedef __attribute__((ext_vector_type(8))) short bf16x8;          // 8 bf16 (4 VGPRs)
typedef __attribute__((ext_vector_type(4))) float f32x4;           // MFMA acc
typedef __attribute__((ext_vector_type(8))) unsigned short us8;    // 16B staging

__device__ __forceinline__ unsigned short f2bf(float f) {  // RNE, finite inputs
  unsigned int u = __float_as_uint(f);
  return (unsigned short)((u + 0x7FFF + ((u >> 16) & 1)) >> 16);
}
__device__ __forceinline__ float bf2f(unsigned short h) {
  return __uint_as_float(((unsigned int)h) << 16);
}

// ---------------- degree / dinv ----------------
__global__ __launch_bounds__(256) void deg_count_kernel(const int* __restrict__ dst,
                                                        int* __restrict__ deg) {
  int i = blockIdx.x * 256 + threadIdx.x;
  if (i < GE) atomicAdd(&deg[dst[i]], 1);
}

__global__ __launch_bounds__(256) void dinv_kernel(const int* __restrict__ deg,
                                                   float* __restrict__ dinv) {
  int i = blockIdx.x * 256 + threadIdx.x;
  if (i < GN) dinv[i] = 1.0f / sqrtf((float)(deg[i] + 1));  // self-loop => deg+1 >= 1
}

// ---------------- hierarchical exclusive scan (n up to GN) ----------------
__global__ __launch_bounds__(256) void scan1_kernel(const int* __restrict__ in,
                                                    int* __restrict__ out,
                                                    int* __restrict__ btot, int n) {
  __shared__ int sh[256];
  int b = blockIdx.x, tid = threadIdx.x;
  int i = b * 256 + tid;
  int v = (i < n) ? in[i] : 0;
  sh[tid] = v;
  __syncthreads();
  for (int ofs = 1; ofs < 256; ofs <<= 1) {
    int t = (tid >= ofs) ? sh[tid - ofs] : 0;
    __syncthreads();
    sh[tid] += t;
    __syncthreads();
  }
  if (i < n) out[i] = sh[tid] - v;  // block-local exclusive
  if (tid == 255) btot[b] = sh[255];
}

__global__ __launch_bounds__(256) void scan2_kernel(int* __restrict__ btot, int nb) {
  __shared__ int sh[256];
  int tid = threadIdx.x;
  int v = (tid < nb) ? btot[tid] : 0;
  sh[tid] = v;
  __syncthreads();
  for (int ofs = 1; ofs < 256; ofs <<= 1) {
    int t = (tid >= ofs) ? sh[tid - ofs] : 0;
    __syncthreads();
    sh[tid] += t;
    __syncthreads();
  }
  if (tid < nb) btot[tid] = sh[tid] - v;  // exclusive block bases
}

__global__ __launch_bounds__(256) void scan3_kernel(int* __restrict__ out,
                                                    const int* __restrict__ btot,
                                                    int n, int total) {
  int b = blockIdx.x, tid = threadIdx.x;
  int i = b * 256 + tid;
  if (i < n) out[i] += btot[b];
  if (i == 0) out[n] = total;
}

// ------------- small strided exclusive scan (n <= few hundred) -------------
__global__ __launch_bounds__(256) void exscan_strided_kernel(const int* __restrict__ in,
                                                             int* __restrict__ out,
                                                             int n, int stride) {
  __shared__ int sh[256];
  __shared__ int carry;
  int tid = threadIdx.x;
  if (tid == 0) carry = 0;
  __syncthreads();
  for (int base = 0; base < n; base += 256) {
    int i = base + tid;
    int v = (i < n) ? in[(size_t)i * stride] : 0;
    sh[tid] = v;
    __syncthreads();
    for (int ofs = 1; ofs < 256; ofs <<= 1) {
      int t = (tid >= ofs) ? sh[tid - ofs] : 0;
      __syncthreads();
      sh[tid] += t;
      __syncthreads();
    }
    if (i < n) out[i] = carry + sh[tid] - v;
    int total = sh[255];
    __syncthreads();
    if (tid == 0) carry += total;
    __syncthreads();
  }
  if (tid == 0) out[n] = carry;
}

// ---------------- CSR fill (bucket edges by dst) ----------------
__global__ __launch_bounds__(256) void csr_fill_kernel(const int* __restrict__ src,
                                                       const int* __restrict__ dst,
                                                       int* __restrict__ cur,
                                                       int* __restrict__ csr_src) {
  int i = blockIdx.x * 256 + threadIdx.x;
  if (i < GE) {
    int j = atomicAdd(&cur[dst[i]], 1);
    csr_src[j] = src[i];
  }
}

// ---------------- seg bucketing for wavelet+pool (PADDED counters) ----------------
__device__ __forceinline__ int seg_of(int row, const int* __restrict__ batch) {
  int sc = row / GN;
  int node = row - sc * GN;
  return sc * GB + batch[node];
}

__global__ __launch_bounds__(256) void seg_cnt_kernel(const int* __restrict__ rows,
                                                      const int* __restrict__ batch,
                                                      int* __restrict__ scnt_p) {
  int i = blockIdx.x * 256 + threadIdx.x;
  if (i < GNNZ) atomicAdd(&scnt_p[(size_t)seg_of(rows[i], batch) * PAD], 1);
}

__global__ __launch_bounds__(256) void scur_init_kernel(const int* __restrict__ soff,
                                                        int* __restrict__ scur_p) {
  int s = blockIdx.x * 256 + threadIdx.x;
  if (s < NSEG) scur_p[(size_t)s * PAD] = soff[s];
}

__global__ __launch_bounds__(256) void seg_fill_kernel(const int* __restrict__ rows,
                                                       const int* __restrict__ cols,
                                                       const float* __restrict__ d,
                                                       const int* __restrict__ batch,
                                                       int* __restrict__ scur_p,
                                                       int* __restrict__ scol,
                                                       float* __restrict__ sd) {
  int i = blockIdx.x * 256 + threadIdx.x;
  if (i < GNNZ) {
    int j = atomicAdd(&scur_p[(size_t)seg_of(rows[i], batch) * PAD], 1);
    scol[j] = cols[i];
    sd[j] = d[i];
  }
}

// ---------------- bf16 hi/lo split conversions ----------------
// a = bf16(a) + bf16(a - bf16(a)) captures ~16 mantissa bits; the 3-term MFMA
// product (Ah*Wh + Ah*Wl + Al*Wh) then has ~2e-5 relative error (lo*lo dropped).
__global__ __launch_bounds__(256) void cvt_hilo_kernel(const float* __restrict__ x,
                                                       unsigned short* __restrict__ hi,
                                                       unsigned short* __restrict__ lo,
                                                       int n) {
  int i = blockIdx.x * 256 + threadIdx.x;  // float4 units
  if (i < (n >> 2)) {
    float4 v = ((const float4*)x)[i];
    ushort4 h, l;
    h.x = f2bf(v.x); l.x = f2bf(v.x - bf2f(h.x));
    h.y = f2bf(v.y); l.y = f2bf(v.y - bf2f(h.y));
    h.z = f2bf(v.z); l.z = f2bf(v.z - bf2f(h.z));
    h.w = f2bf(v.w); l.w = f2bf(v.w - bf2f(h.w));
    ((ushort4*)hi)[i] = h;
    ((ushort4*)lo)[i] = l;
  }
}

// W[K][256] -> Wt_hi/lo[256][K] (transpose + split; tiny, scattered writes OK)
template <int K>
__global__ __launch_bounds__(256) void cvt_wt_kernel(const float* __restrict__ W,
                                                     unsigned short* __restrict__ wth,
                                                     unsigned short* __restrict__ wtl) {
  int idx = blockIdx.x * 256 + threadIdx.x;
  if (idx < K * GH) {
    int k = idx / GH, c = idx - k * GH;
    float f = W[idx];
    unsigned short h = f2bf(f);
    wth[(size_t)c * K + k] = h;
    wtl[(size_t)c * K + k] = f2bf(f - bf2f(h));
  }
}

// -------- split-bf16 MFMA GEMM: C[M][256] = (Ah+Al)[M][K] @ (Wh+Wl)[K][256] ----
// 128x128 tile, 4 waves (2x2, 64x64 each), BK=32 = one mfma_16x16x32 K-chunk.
// LDS rows padded to 40 ushorts (80B) -> frag ds_read_b128 aliases max 2 lanes/bank.
// Fragment layouts (guide §3, m89-verified C/D): A: lane holds A[l&15][(l>>4)*8+j];
// B (stored transposed): lane holds W[(l>>4)*8+j][l&15]; D: col=l&15, row=(l>>4)*4+r.
// r12 BUG FIX: staging now covers all 32 k-elems/row (was covering only k[0..7],
// k[16..23] -> half the LDS tile was stale garbage -> absmax 0.69 fail).
#define LDP 40
template <int K>
__global__ __launch_bounds__(256) void gemm_mfma_kernel(
    const unsigned short* __restrict__ Ah, const unsigned short* __restrict__ Al,
    const unsigned short* __restrict__ Bth, const unsigned short* __restrict__ Btl,
    float* __restrict__ C, int M) {
  __shared__ unsigned short sAh[128 * LDP], sAl[128 * LDP];
  __shared__ unsigned short sBh[128 * LDP], sBl[128 * LDP];
  int tid = threadIdx.x;
  int col0 = blockIdx.x * 128;
  int row0 = blockIdx.y * 128;
  int wave = tid >> 6, lane = tid & 63;
  int wr = wave >> 1, wc = wave & 1;  // 2x2 wave grid, each 64x64
  int lr = lane & 15;                 // fragment row (A) / col (B)
  int kg = lane >> 4;                 // k-group (8 bf16 each)
  f32x4 acc[4][4] = {};               // [mi][ni] 16x16 fragments

  for (int kk = 0; kk < K; kk += 32) {
    __syncthreads();  // previous-iter reads done before overwrite
#pragma unroll
    for (int l = 0; l < 2; ++l) {
      int idx = tid + l * 256;   // 0..511: 128 rows x 4 us8-chunks of 8 elems
      int r = idx >> 2;          // row 0..127
      int ko = (idx & 3) * 8;    // k offset 0,8,16,24
      int arow = row0 + r; if (arow >= M) arow = M - 1;
      size_t ga = (size_t)arow * K + kk + ko;
      *(us8*)&sAh[r * LDP + ko] = *(const us8*)&Ah[ga];
      *(us8*)&sAl[r * LDP + ko] = *(const us8*)&Al[ga];
      size_t gb = (size_t)(col0 + r) * K + kk + ko;
      *(us8*)&sBh[r * LDP + ko] = *(const us8*)&Bth[gb];
      *(us8*)&sBl[r * LDP + ko] = *(const us8*)&Btl[gb];
    }
    __syncthreads();
    bf16x8 ah[4], al[4], bh[4], bl[4];
#pragma unroll
    for (int mi = 0; mi < 4; ++mi) {
      int r = wr * 64 + mi * 16 + lr;
      ah[mi] = *(const bf16x8*)&sAh[r * LDP + kg * 8];
      al[mi] = *(const bf16x8*)&sAl[r * LDP + kg * 8];
    }
#pragma unroll
    for (int ni = 0; ni < 4; ++ni) {
      int c = wc * 64 + ni * 16 + lr;
      bh[ni] = *(const bf16x8*)&sBh[c * LDP + kg * 8];
      bl[ni] = *(const bf16x8*)&sBl[c * LDP + kg * 8];
    }
#pragma unroll
    for (int mi = 0; mi < 4; ++mi)
#pragma unroll
      for (int ni = 0; ni < 4; ++ni) {
        acc[mi][ni] = __builtin_amdgcn_mfma_f32_16x16x32_bf16(ah[mi], bh[ni], acc[mi][ni], 0, 0, 0);
        acc[mi][ni] = __builtin_amdgcn_mfma_f32_16x16x32_bf16(ah[mi], bl[ni], acc[mi][ni], 0, 0, 0);
        acc[mi][ni] = __builtin_amdgcn_mfma_f32_16x16x32_bf16(al[mi], bh[ni], acc[mi][ni], 0, 0, 0);
      }
  }
#pragma unroll
  for (int mi = 0; mi < 4; ++mi) {
    int rbase = row0 + wr * 64 + mi * 16 + kg * 4;
#pragma unroll
    for (int ni = 0; ni < 4; ++ni) {
      int c = col0 + wc * 64 + ni * 16 + lr;
#pragma unroll
      for (int r4 = 0; r4 < 4; ++r4) {
        int r = rbase + r4;
        if (r < M) C[(size_t)r * GH + c] = acc[mi][ni][r4];
      }
    }
  }
}

// ------------- GCN aggregation: gather + self-loop + bias + relu -------------
__global__ __launch_bounds__(256) void agg_kernel(const float* __restrict__ m,
                                                  const float* __restrict__ dinv,
                                                  const int* __restrict__ off,
                                                  const int* __restrict__ srcs,
                                                  const float* __restrict__ bias,
                                                  float* __restrict__ out) {
  int node = blockIdx.x * 4 + (threadIdx.x >> 6);
  if (node >= GN) return;
  int lane = threadIdx.x & 63;
  float4 acc = *(const float4*)&bias[lane * 4];
  float di = dinv[node];
  float w0 = di * di;  // self-loop norm
  float4 mv = *(const float4*)&m[(size_t)node * GH + lane * 4];
  acc.x += w0 * mv.x; acc.y += w0 * mv.y; acc.z += w0 * mv.z; acc.w += w0 * mv.w;
  int e0 = off[node], e1 = off[node + 1];
  int e = e0;
  for (; e + 2 <= e1; e += 2) {  // unroll-by-2: two row loads in flight
    int s0 = srcs[e], s1 = srcs[e + 1];
    float w0a = di * dinv[s0];
    float w1a = di * dinv[s1];
    float4 v0 = *(const float4*)&m[(size_t)s0 * GH + lane * 4];
    float4 v1 = *(const float4*)&m[(size_t)s1 * GH + lane * 4];
    acc.x += w0a * v0.x + w1a * v1.x;
    acc.y += w0a * v0.y + w1a * v1.y;
    acc.z += w0a * v0.z + w1a * v1.z;
    acc.w += w0a * v0.w + w1a * v1.w;
  }
  if (e < e1) {
    int s = srcs[e];
    float w = di * dinv[s];
    float4 v = *(const float4*)&m[(size_t)s * GH + lane * 4];
    acc.x += w * v.x; acc.y += w * v.y; acc.z += w * v.z; acc.w += w * v.w;
  }
  acc.x = fmaxf(acc.x, 0.f); acc.y = fmaxf(acc.y, 0.f);
  acc.z = fmaxf(acc.z, 0.f); acc.w = fmaxf(acc.w, 0.f);
  *(float4*)&out[(size_t)node * GH + lane * 4] = acc;
}

// ------- fused wavelet transform + per-(scale,graph) pooling gather -------
// MEASURED 162-165 us (r2/r10/r11). Staged 256-nnz chunks -> fixed-trip inner
// loop gives compiler-pipelined independent h loads. Read-once LDS-scatter
// variants (r7/r9) collapsed to ~1.5 ms (no MLP on dependent chains).
__global__ __launch_bounds__(256) void pooled_kernel(const float* __restrict__ h,
                                                     const int* __restrict__ soff,
                                                     const int* __restrict__ scol,
                                                     const float* __restrict__ sd,
                                                     float* __restrict__ pooled) {
  __shared__ int lcol[256];
  __shared__ float ld[256];
  int seg = blockIdx.x;
  int j0 = soff[seg], j1 = soff[seg + 1];
  int cnt = j1 - j0;
  int nparts = gridDim.y;
  int per = (cnt + nparts - 1) / nparts;
  int s = j0 + blockIdx.y * per;
  int e = s + per;
  if (e > j1) e = j1;
  int tid = threadIdx.x;
  float acc = 0.f;
  for (int base = s; base < e; base += 256) {
    int nload = e - base;
    if (nload > 256) nload = 256;
    __syncthreads();
    if (tid < nload) {
      lcol[tid] = scol[base + tid];
      ld[tid] = sd[base + tid];
    }
    __syncthreads();
    for (int t = 0; t < nload; ++t) {
      acc += ld[t] * h[(size_t)lcol[t] * GH + tid];
    }
  }
  atomicAdd(&pooled[(size_t)seg * GH + tid], acc);
}

// ---------------- FC head ----------------
__global__ __launch_bounds__(256) void fc1_kernel(const float* __restrict__ pooled,
                                                  const float* __restrict__ w,
                                                  const float* __restrict__ b,
                                                  float* __restrict__ z1) {
  __shared__ float vin[GSCALE * GH];  // 768
  int g = blockIdx.x, tid = threadIdx.x;
#pragma unroll
  for (int it = 0; it < GSCALE; ++it)
    vin[it * GH + tid] = pooled[(size_t)(it * GB + g) * GH + tid];
  __syncthreads();
  float acc = b[tid];
  for (int j = 0; j < GSCALE * GH; ++j) acc += vin[j] * w[(size_t)j * GH + tid];
  z1[(size_t)g * GH + tid] = fmaxf(acc, 0.f);
}

__global__ __launch_bounds__(128) void fc2_kernel(const float* __restrict__ z1,
                                                  const float* __restrict__ w,
                                                  const float* __restrict__ b,
                                                  float* __restrict__ z2) {
  __shared__ float vin[GH];
  int g = blockIdx.x, tid = threadIdx.x;  // 128 threads
  vin[tid] = z1[(size_t)g * GH + tid];
  vin[128 + tid] = z1[(size_t)g * GH + 128 + tid];
  __syncthreads();
  float acc = b[tid];
  for (int j = 0; j < GH; ++j) acc += vin[j] * w[(size_t)j * 128 + tid];
  z2[(size_t)g * 128 + tid] = fmaxf(acc, 0.f);
}

__global__ __launch_bounds__(128) void fc3_kernel(const float* __restrict__ z2,
                                                  const float* __restrict__ w,
                                                  const float* __restrict__ b,
                                                  float* __restrict__ out) {
  int g = threadIdx.x;  // one thread per graph, 1 block of 128
  float logit[NCLS];
#pragma unroll
  for (int o = 0; o < NCLS; ++o) logit[o] = b[o];
  for (int k = 0; k < 128; ++k) {
    float zv = z2[(size_t)g * 128 + k];
#pragma unroll
    for (int o = 0; o < NCLS; ++o) logit[o] += zv * w[k * NCLS + o];
  }
  float mx = logit[0];
#pragma unroll
  for (int o = 1; o < NCLS; ++o) mx = fmaxf(mx, logit[o]);
  float lse = 0.f;
#pragma unroll
  for (int o = 0; o < NCLS; ++o) lse += expf(logit[o] - mx);
  lse = logf(lse);
#pragma unroll
  for (int o = 0; o < NCLS; ++o) out[(size_t)g * NCLS + o] = logit[o] - mx - lse;
}

// ---------------- launch ----------------
static inline size_t alignup(size_t x) { return (x + 1023) & ~(size_t)1023; }

extern "C" void kernel_launch(void* const* d_in, const int* in_sizes, int n_in,
                              void* d_out, int out_size, void* d_ws, size_t ws_size,
                              hipStream_t stream) {
  const float* x      = (const float*)d_in[0];
  const float* W1     = (const float*)d_in[1];
  const float* b1     = (const float*)d_in[2];
  const float* W2     = (const float*)d_in[3];
  const float* b2     = (const float*)d_in[4];
  const float* W3     = (const float*)d_in[5];
  const float* b3     = (const float*)d_in[6];
  const float* fc1w   = (const float*)d_in[7];
  const float* fc1b   = (const float*)d_in[8];
  const float* fc2w   = (const float*)d_in[9];
  const float* fc2b   = (const float*)d_in[10];
  const float* fc3w   = (const float*)d_in[11];
  const float* fc3b   = (const float*)d_in[12];
  const float* dval   = (const float*)d_in[13];
  const int* eidx     = (const int*)d_in[14];
  const int* batch    = (const int*)d_in[15];
  const int* didx     = (const int*)d_in[16];
  float* out          = (float*)d_out;

  const int* esrc = eidx;             // edge_index[0]
  const int* edst = eidx + GE;        // edge_index[1]
  const int* nzrow = didx;            // d_index[0]
  const int* nzcol = didx + GNNZ;     // d_index[1]

  // workspace carve-up
  char* ws = (char*)d_ws;
  size_t o = 0;
  auto take = [&](size_t bytes) { char* p = ws + o; o += alignup(bytes); return p; };
  int*   deg     = (int*)take(GN * 4);
  int*   off     = (int*)take((GN + 1) * 4);
  int*   cur     = (int*)take(GN * 4);
  int*   btot    = (int*)take(256 * 4);
  float* dinv    = (float*)take(GN * 4);
  int*   csr_src = (int*)take(GE * 4);
  int*   scnt_p  = (int*)take(NSEG * PAD * 4);
  int*   soff    = (int*)take((NSEG + 1) * 4);
  int*   scur_p  = (int*)take(NSEG * PAD * 4);
  int*   scol    = (int*)take((size_t)GNNZ * 4);
  float* sd      = (float*)take((size_t)GNNZ * 4);
  unsigned short* wt1h = (unsigned short*)take((size_t)FIN * GH * 2);
  unsigned short* wt1l = (unsigned short*)take((size_t)FIN * GH * 2);
  unsigned short* wt2h = (unsigned short*)take((size_t)GH * GH * 2);
  unsigned short* wt2l = (unsigned short*)take((size_t)GH * GH * 2);
  unsigned short* wt3h = (unsigned short*)take((size_t)GH * GH * 2);
  unsigned short* wt3l = (unsigned short*)take((size_t)GH * GH * 2);
  float* mbuf    = (float*)take((size_t)GN * GH * 4);
  float* hA      = (float*)take((size_t)GN * GH * 4);
  float* hB      = (float*)take((size_t)GN * GH * 4);
  float* pooled  = (float*)take((size_t)NSEG * GH * 4);
  float* z1      = (float*)take((size_t)GB * GH * 4);
  float* z2      = (float*)take((size_t)GB * 128 * 4);
  (void)ws_size; (void)n_in; (void)in_sizes; (void)out_size;

  // bf16 hi/lo staging buffers alias dead fp32 buffers (stream-ordered safety):
  //  layer1: xh/xl in hA   (hA written by agg1 AFTER gemm1 consumed xh/xl)
  //  layer2: a2 in hB      (hB written by agg2 AFTER gemm2)
  //  layer3: a3 in hA      (hA's fp32 dead after layer-2 cvt; agg3 rewrites it)
  unsigned short* xh  = (unsigned short*)hA;
  unsigned short* xl  = xh + (size_t)GN * FIN;
  unsigned short* a2h = (unsigned short*)hB;
  unsigned short* a2l = a2h + (size_t)GN * GH;
  unsigned short* a3h = (unsigned short*)hA;
  unsigned short* a3l = a3h + (size_t)GN * GH;

  const int NB = (GN + 255) / 256;  // 196

  // ---- graph prep (once per call) ----
  hipMemsetAsync(deg, 0, GN * 4, stream);
  hipMemsetAsync(scnt_p, 0, NSEG * PAD * 4, stream);
  hipMemsetAsync(pooled, 0, (size_t)NSEG * GH * 4, stream);

  deg_count_kernel<<<GE / 256, 256, 0, stream>>>(edst, deg);
  dinv_kernel<<<NB, 256, 0, stream>>>(deg, dinv);
  scan1_kernel<<<NB, 256, 0, stream>>>(deg, off, btot, GN);
  scan2_kernel<<<1, 256, 0, stream>>>(btot, NB);
  scan3_kernel<<<NB, 256, 0, stream>>>(off, btot, GN, GE);
  hipMemcpyAsync(cur, off, GN * 4, hipMemcpyDeviceToDevice, stream);
  csr_fill_kernel<<<GE / 256, 256, 0, stream>>>(esrc, edst, cur, csr_src);

  seg_cnt_kernel<<<(GNNZ + 255) / 256, 256, 0, stream>>>(nzrow, batch, scnt_p);
  exscan_strided_kernel<<<1, 256, 0, stream>>>(scnt_p, soff, NSEG, PAD);
  scur_init_kernel<<<(NSEG + 255) / 256, 256, 0, stream>>>(soff, scur_p);
  seg_fill_kernel<<<(GNNZ + 255) / 256, 256, 0, stream>>>(nzrow, nzcol, dval, batch,
                                                          scur_p, scol, sd);

  // ---- weight transpose + bf16 split (tiny) ----
  cvt_wt_kernel<FIN><<<(FIN * GH + 255) / 256, 256, 0, stream>>>(W1, wt1h, wt1l);
  cvt_wt_kernel<GH><<<(GH * GH + 255) / 256, 256, 0, stream>>>(W2, wt2h, wt2l);
  cvt_wt_kernel<GH><<<(GH * GH + 255) / 256, 256, 0, stream>>>(W3, wt3h, wt3l);

  // ---- 3 GCN layers: split-bf16 MFMA GEMM + fp32 gather-agg ----
  dim3 mgrid(GH / 128, (GN + 127) / 128);  // (2, 391)
  cvt_hilo_kernel<<<(GN * FIN / 4 + 255) / 256, 256, 0, stream>>>(x, xh, xl, GN * FIN);
  gemm_mfma_kernel<FIN><<<mgrid, 256, 0, stream>>>(xh, xl, wt1h, wt1l, mbuf, GN);
  agg_kernel<<<(GN + 3) / 4, 256, 0, stream>>>(mbuf, dinv, off, csr_src, b1, hA);

  cvt_hilo_kernel<<<(GN * GH / 4 + 255) / 256, 256, 0, stream>>>(hA, a2h, a2l, GN * GH);
  gemm_mfma_kernel<GH><<<mgrid, 256, 0, stream>>>(a2h, a2l, wt2h, wt2l, mbuf, GN);
  agg_kernel<<<(GN + 3) / 4, 256, 0, stream>>>(mbuf, dinv, off, csr_src, b2, hB);

  cvt_hilo_kernel<<<(GN * GH / 4 + 255) / 256, 256, 0, stream>>>(hB, a3h, a3l, GN * GH);
  gemm_mfma_kernel<GH><<<mgrid, 256, 0, stream>>>(a3h, a3l, wt3h, wt3l, mbuf, GN);
  agg_kernel<<<(GN + 3) / 4, 256, 0, stream>>>(mbuf, dinv, off, csr_src, b3, hA);

  // ---- fused wavelet + pooling (hA holds final node features) ----
  pooled_kernel<<<dim3(NSEG, 8), 256, 0, stream>>>(hA, soff, scol, sd, pooled);

  // ---- FC head ----
  fc1_kernel<<<GB, 256, 0, stream>>>(pooled, fc1w, fc1b, z1);
  fc2_kernel<<<GB, 128, 0, stream>>>(z1, fc2w, fc2b, z2);
  fc3_kernel<<<1, 128, 0, stream>>>(z2, fc3w, fc3b, out);
}